// Round 10
// baseline (324.207 us; speedup 1.0000x reference)
//
#include <hip/hip_runtime.h>
#include <hip/hip_bf16.h>
#include <cstdint>
#include <cstddef>

typedef __bf16 bf16_t;
typedef __attribute__((ext_vector_type(8))) __bf16 bf16x8;
typedef __attribute__((ext_vector_type(4))) __bf16 bf16x4;
typedef __attribute__((ext_vector_type(4))) float f32x4;

#define B_ 2
#define T_ 2048
#define DIM_ 2048
#define H_ 16
#define DH_ 128
#define DD_ 64
#define DQK_ 192              // DH_ + DD_
#define QSTRIDE_ 3072         // H_ * DQK_
#define BT_ 4096              // B_ * T_

__device__ __forceinline__ void gload16(const void* g, void* lds) {
  __builtin_amdgcn_global_load_lds(
      (const __attribute__((address_space(1))) unsigned int*)g,
      (__attribute__((address_space(3))) unsigned int*)lds, 16, 0, 0);
}

struct bf16_4 { bf16_t a, b, c, d; };

// ------------- prep: ALL weight transposes + x cast in ONE launch -------------
__global__ void prep(const float* __restrict__ x,
                     const float* __restrict__ Wdq, const float* __restrict__ Wdkv,
                     const float* __restrict__ Wkr, const float* __restrict__ Wuq,
                     const float* __restrict__ Wqr, const float* __restrict__ Wuk,
                     const float* __restrict__ Wuv, const float* __restrict__ Wo,
                     bf16_t* __restrict__ x_bf,
                     bf16_t* __restrict__ Bt1, bf16_t* __restrict__ Bt2,
                     bf16_t* __restrict__ Bt3, bf16_t* __restrict__ Wo_t) {
  int id = blockIdx.x;
  if (id >= 9984) {
    // cast x fp32 -> bf16, float4-vectorized; exactly BT_*DIM_/4 threads
    int i = (id - 9984) * 256 + threadIdx.y * 32 + threadIdx.x;
    float4 v = ((const float4*)x)[i];
    bf16_4 r{(bf16_t)v.x, (bf16_t)v.y, (bf16_t)v.z, (bf16_t)v.w};
    ((bf16_4*)x_bf)[i] = r;
    return;
  }
  __shared__ float tile[32][33];
  const float* W; bf16_t* Wt; int K, N, Np, kt;
  if (id < 1024)      { W = Wdq;  Wt = Bt1;                          K = 2048; N = 512;  Np = 512;  kt = 64; }
  else if (id < 2048) { W = Wdkv; Wt = Bt1 + (size_t)512 * 2048;  id -= 1024; K = 2048; N = 512;  Np = 512;  kt = 64; }
  else if (id < 2304) { W = Wkr;  Wt = Bt1 + (size_t)1024 * 2048; id -= 2048; K = 2048; N = 64;   Np = 128;  kt = 64; }
  else if (id < 3328) { W = Wuq;  Wt = Bt2;                       id -= 2304; K = 512;  N = 2048; Np = 2048; kt = 16; }
  else if (id < 3840) { W = Wqr;  Wt = Bt2 + (size_t)2048 * 512;  id -= 3328; K = 512;  N = 1024; Np = 1024; kt = 16; }
  else if (id < 4864) { W = Wuk;  Wt = Bt3;                       id -= 3840; K = 512;  N = 2048; Np = 2048; kt = 16; }
  else if (id < 5888) { W = Wuv;  Wt = Bt3 + (size_t)2048 * 512;  id -= 4864; K = 512;  N = 2048; Np = 2048; kt = 16; }
  else                { W = Wo;   Wt = Wo_t;                      id -= 5888; K = 2048; N = 2048; Np = 2048; kt = 64; }
  int k0 = (id % kt) * 32, n0 = (id / kt) * 32;
  int tx = threadIdx.x, ty = threadIdx.y;
#pragma unroll
  for (int i = 0; i < 4; ++i) {
    int k = k0 + ty + i * 8, n = n0 + tx;
    float v = (k < K && n < N) ? W[(size_t)k * N + n] : 0.f;
    tile[ty + i * 8][tx] = v;
  }
  __syncthreads();
#pragma unroll
  for (int i = 0; i < 4; ++i) {
    int n = n0 + ty + i * 8, k = k0 + tx;
    if (n < Np && k < K) Wt[(size_t)n * K + k] = (bf16_t)tile[tx][ty + i * 8];
  }
}

// ---------------- GEMM template (MODE 1: fp32 out; MODE 3: q_c/kv_c + fused rope-k broadcast) ----------------
template <int MODE>
__global__ __launch_bounds__(256) void gemm_bt(const bf16_t* __restrict__ A,
                                               const bf16_t* __restrict__ Bt,
                                               void* __restrict__ C0v,
                                               void* __restrict__ C1v,
                                               void* __restrict__ C2v,
                                               const float* __restrict__ fr,
                                               int M, int N, int K, int ldc) {
  __shared__ bf16_t As[128 * 32];
  __shared__ bf16_t Bs[128 * 32];
  const int t = threadIdx.x;
  const int w = t >> 6, l = t & 63, l15 = l & 15, lhi = l >> 4;
  const int m0 = blockIdx.y * 128, n0 = blockIdx.x * 128;
  const int wr = (w >> 1) * 64, wc = (w & 1) * 64;

  f32x4 zero = {0.f, 0.f, 0.f, 0.f};
  f32x4 acc[4][4];
#pragma unroll
  for (int m = 0; m < 4; ++m)
#pragma unroll
    for (int n = 0; n < 4; ++n) acc[m][n] = zero;

  const int e0 = t * 8;
  const int r0 = e0 >> 5, c0 = e0 & 31;
  const int e1 = 2048 + t * 8;
  const int r1 = e1 >> 5, c1 = e1 & 31;

  for (int k0 = 0; k0 < K; k0 += 32) {
    gload16(A + (size_t)(m0 + r0) * K + k0 + c0, &As[e0]);
    gload16(A + (size_t)(m0 + r1) * K + k0 + c1, &As[e1]);
    gload16(Bt + (size_t)(n0 + r0) * K + k0 + c0, &Bs[e0]);
    gload16(Bt + (size_t)(n0 + r1) * K + k0 + c1, &Bs[e1]);
    __syncthreads();
    bf16x8 af[4], bfr[4];
#pragma unroll
    for (int m = 0; m < 4; ++m)
      af[m] = *(const bf16x8*)&As[(wr + m * 16 + l15) * 32 + lhi * 8];
#pragma unroll
    for (int n = 0; n < 4; ++n)
      bfr[n] = *(const bf16x8*)&Bs[(wc + n * 16 + l15) * 32 + lhi * 8];
#pragma unroll
    for (int m = 0; m < 4; ++m)
#pragma unroll
      for (int n = 0; n < 4; ++n)
        acc[m][n] = __builtin_amdgcn_mfma_f32_16x16x32_bf16(af[m], bfr[n], acc[m][n], 0, 0, 0);
    __syncthreads();
  }

#pragma unroll
  for (int m = 0; m < 4; ++m) {
#pragma unroll
    for (int n = 0; n < 4; ++n) {
#pragma unroll
      for (int r = 0; r < 4; ++r) {
        int row = m0 + wr + m * 16 + lhi * 4 + r;
        int col = n0 + wc + n * 16 + l15;
        float v = acc[m][n][r];
        if (MODE == 1) {
          ((float*)C0v)[(size_t)row * ldc + col] = v;
        } else if (MODE == 3) {
          if (col < 512) {
            ((bf16_t*)C0v)[(size_t)row * 512 + col] = (bf16_t)v;
          } else if (col < 1024) {
            ((bf16_t*)C1v)[(size_t)row * 512 + (col - 512)] = (bf16_t)v;
          } else if (col < 1088) {
            // fused rope-k: rotate pair (adjacent l15 lanes) then broadcast to all 16 heads
            float other = __shfl_xor(v, 1, 64);
            int tt = row & (T_ - 1);
            int j = (col - 1024) >> 1;
            float2 cs = ((const float2*)fr)[tt * 32 + j];
            float o = (col & 1) ? (other * cs.y + v * cs.x) : (v * cs.x - other * cs.y);
            float o2 = __shfl_xor(o, 1, 64);
            if (!(col & 1)) {
              union { bf16_t h2[2]; unsigned u; } pk;
              pk.h2[0] = (bf16_t)o;
              pk.h2[1] = (bf16_t)o2;
              bf16_t* Kb = (bf16_t*)C2v;
#pragma unroll
              for (int hh = 0; hh < H_; ++hh)
                *(unsigned*)&Kb[(size_t)row * QSTRIDE_ + hh * DQK_ + 128 + (col - 1024)] = pk.u;
            }
          }
        }
      }
    }
  }
}

// ---------------- fused gemm4+gemm5: one dispatch ----------------
// blocks x<24: Qbuf (q_c @ Bt2, N=3072): col<2048 head-interleaved, else in-reg rope-q.
// blocks x>=24: kv_c @ Bt3 (N=4096): col<2048 -> Kbuf head-interleaved;
//               col>=2048 -> V, transposed IN-EPILOGUE via LDS -> Vt[bh][128][T].
__global__ __launch_bounds__(256) void gemm45(const bf16_t* __restrict__ q_c,
                                              const bf16_t* __restrict__ kv_c,
                                              const bf16_t* __restrict__ Bt2,
                                              const bf16_t* __restrict__ Bt3,
                                              bf16_t* __restrict__ Qbuf,
                                              bf16_t* __restrict__ Kbuf,
                                              bf16_t* __restrict__ Vt,
                                              const float* __restrict__ fr) {
  __shared__ bf16_t As[128 * 32];
  __shared__ bf16_t Bs[128 * 32];
  __shared__ bf16_t ctile[64 * 136];  // V-transpose staging (padded: 272B rows, 16B-aligned)
  const int t = threadIdx.x;
  const int w = t >> 6, l = t & 63, l15 = l & 15, lhi = l >> 4;
  const bool isQ = (blockIdx.x < 24);
  const int bx = isQ ? blockIdx.x : blockIdx.x - 24;
  const bf16_t* A  = isQ ? q_c : kv_c;
  const bf16_t* Bt = isQ ? Bt2 : Bt3;
  constexpr int K = 512;
  const int m0 = blockIdx.y * 128, n0 = bx * 128;
  const int wr = (w >> 1) * 64, wc = (w & 1) * 64;

  f32x4 zero = {0.f, 0.f, 0.f, 0.f};
  f32x4 acc[4][4];
#pragma unroll
  for (int m = 0; m < 4; ++m)
#pragma unroll
    for (int n = 0; n < 4; ++n) acc[m][n] = zero;

  const int e0 = t * 8;
  const int r0 = e0 >> 5, c0 = e0 & 31;
  const int e1 = 2048 + t * 8;
  const int r1 = e1 >> 5, c1 = e1 & 31;

  for (int k0 = 0; k0 < K; k0 += 32) {
    gload16(A + (size_t)(m0 + r0) * K + k0 + c0, &As[e0]);
    gload16(A + (size_t)(m0 + r1) * K + k0 + c1, &As[e1]);
    gload16(Bt + (size_t)(n0 + r0) * K + k0 + c0, &Bs[e0]);
    gload16(Bt + (size_t)(n0 + r1) * K + k0 + c1, &Bs[e1]);
    __syncthreads();
    bf16x8 af[4], bfr[4];
#pragma unroll
    for (int m = 0; m < 4; ++m)
      af[m] = *(const bf16x8*)&As[(wr + m * 16 + l15) * 32 + lhi * 8];
#pragma unroll
    for (int n = 0; n < 4; ++n)
      bfr[n] = *(const bf16x8*)&Bs[(wc + n * 16 + l15) * 32 + lhi * 8];
#pragma unroll
    for (int m = 0; m < 4; ++m)
#pragma unroll
      for (int n = 0; n < 4; ++n)
        acc[m][n] = __builtin_amdgcn_mfma_f32_16x16x32_bf16(af[m], bfr[n], acc[m][n], 0, 0, 0);
    __syncthreads();
  }

  const bool isV = (!isQ) && (bx >= 16);
  if (!isV) {
#pragma unroll
    for (int m = 0; m < 4; ++m) {
#pragma unroll
      for (int n = 0; n < 4; ++n) {
#pragma unroll
        for (int r = 0; r < 4; ++r) {
          int row = m0 + wr + m * 16 + lhi * 4 + r;
          int col = n0 + wc + n * 16 + l15;
          float v = acc[m][n][r];
          if (isQ) {
            if (col < 2048) {
              Qbuf[(size_t)row * QSTRIDE_ + (col >> 7) * DQK_ + (col & 127)] = (bf16_t)v;
            } else {
              float other = __shfl_xor(v, 1, 64);
              int tt = row & (T_ - 1);
              int j = (col & 63) >> 1;
              float2 cs = ((const float2*)fr)[tt * 32 + j];
              float o = (col & 1) ? (other * cs.y + v * cs.x) : (v * cs.x - other * cs.y);
              int hh = (col - 2048) >> 6;
              Qbuf[(size_t)row * QSTRIDE_ + hh * DQK_ + 128 + (col & 63)] = (bf16_t)o;
            }
          } else {
            Kbuf[(size_t)row * QSTRIDE_ + (col >> 7) * DQK_ + (col & 127)] = (bf16_t)v;
          }
        }
      }
    }
  } else {
    // V tile: cols n0..n0+127 = head h, feature d 0..127; rows = token t (batch-local!).
    const int h = bx - 16;
    const int b = m0 >> 11;          // T_=2048 rows per batch
    const int bh = b * 16 + h;
    const int tloc = m0 & (T_ - 1);  // batch-local token base (R9 bug: used absolute m0)
#pragma unroll
    for (int half = 0; half < 2; ++half) {
      if ((w & 1) == half) {
        // this wave's cols are d_local = n*16+l15 in [0,64); rows wr + m*16+lhi*4+r
#pragma unroll
        for (int m = 0; m < 4; ++m)
#pragma unroll
          for (int n = 0; n < 4; ++n)
#pragma unroll
            for (int r = 0; r < 4; ++r)
              ctile[(n * 16 + l15) * 136 + wr + m * 16 + lhi * 4 + r] = (bf16_t)acc[m][n][r];
      }
      __syncthreads();
      // all 256 threads: coalesced b128 reads along t, write Vt rows
#pragma unroll
      for (int it = 0; it < 4; ++it) {
        int d = (t >> 4) + it * 16;        // 0..63
        int t0 = (t & 15) * 8;             // 0..120
        bf16x8 v = *(const bf16x8*)&ctile[d * 136 + t0];
        *(bf16x8*)&Vt[((size_t)bh * DH_ + half * 64 + d) * T_ + tloc + t0] = v;
      }
      __syncthreads();
    }
  }
}

// ---------------- causal flash attention v3 (proven ~118 us) ----------------
#define KLDB 200
#define VLDB 72
#define PLDB 68

__global__ __launch_bounds__(256, 2) void flash_attn3(const bf16_t* __restrict__ Q,
                                                      const bf16_t* __restrict__ Kb,
                                                      const bf16_t* __restrict__ Vt,
                                                      bf16_t* __restrict__ Ob) {
  __shared__ bf16_t Ks[64 * KLDB];
  __shared__ bf16_t Vs[128 * VLDB];
  __shared__ bf16_t Ps[4][16 * PLDB];

  const int t = threadIdx.x, w = t >> 6, l = t & 63, l15 = l & 15, lhi = l >> 4;
  const int id = blockIdx.x;
  const int xcd = id & 7, sub = id >> 3;
  const int bh = xcd * 4 + (sub >> 4);
  const int qp = sub & 15;
  const int b = bh >> 4, h = bh & 15;
  const int qa = qp, qb = 31 - qp;  // qa < qb always
  const float scale = 0.07216878364870322f;  // 1/sqrt(192)

  int rK[6], cK[6];
#pragma unroll
  for (int i = 0; i < 6; ++i) { int idx = i * 256 + t; rK[i] = idx / 24; cK[i] = idx % 24; }
  const int rVt = t >> 3, cV = t & 7;
  const bf16_t* kbase = Kb + (size_t)b * T_ * QSTRIDE_ + h * DQK_;
  const bf16_t* vbase = Vt + (size_t)bh * DH_ * T_;

  bf16x8 kreg[6], vreg[4];
#define LOAD_TILE(K0)                                                                      \
  do {                                                                                     \
    _Pragma("unroll") for (int i = 0; i < 6; ++i)                                          \
        kreg[i] = *(const bf16x8*)(kbase + (size_t)((K0) + rK[i]) * QSTRIDE_ + cK[i] * 8); \
    _Pragma("unroll") for (int i = 0; i < 4; ++i)                                          \
        vreg[i] = *(const bf16x8*)(vbase + (size_t)(i * 32 + rVt) * T_ + (K0) + cV * 8);   \
  } while (0)
#define WRITE_TILE()                                                                       \
  do {                                                                                     \
    _Pragma("unroll") for (int i = 0; i < 6; ++i)                                          \
        *(bf16x8*)&Ks[rK[i] * KLDB + cK[i] * 8] = kreg[i];                                 \
    _Pragma("unroll") for (int i = 0; i < 4; ++i)                                          \
        *(bf16x8*)&Vs[(i * 32 + rVt) * VLDB + cV * 8] = vreg[i];                           \
  } while (0)

  f32x4 zero = {0.f, 0.f, 0.f, 0.f};

  LOAD_TILE(0);
  WRITE_TILE();
  __syncthreads();

  for (int pass = 0; pass < 2; ++pass) {
    const int qt = pass ? qb : qa;

    bf16x8 qf[6];
    {
      const bf16_t* qrow = Q + ((size_t)(b * T_ + qt * 64 + w * 16 + l15)) * QSTRIDE_ + h * DQK_;
#pragma unroll
      for (int kc = 0; kc < 6; ++kc) qf[kc] = *(const bf16x8*)(qrow + kc * 32 + lhi * 8);
    }

    float m_r[4], l_r[4];
    f32x4 accO[8];
#pragma unroll
    for (int r = 0; r < 4; ++r) { m_r[r] = -1e30f; l_r[r] = 0.f; }
#pragma unroll
    for (int n = 0; n < 8; ++n) accO[n] = zero;

    for (int kt = 0; kt <= qt; ++kt) {
      const bool last = (kt == qt);
      const bool haveNext = !(pass == 1 && last);
      if (haveNext) LOAD_TILE(last ? 0 : (kt + 1) * 64);  // prefetch (tile 0 for next pass)

      f32x4 s[4];
#pragma unroll
      for (int n = 0; n < 4; ++n) s[n] = zero;
      __builtin_amdgcn_s_setprio(1);
#pragma unroll
      for (int kc = 0; kc < 6; ++kc) {
#pragma unroll
        for (int n = 0; n < 4; ++n) {
          bf16x8 kf = *(const bf16x8*)&Ks[(n * 16 + l15) * KLDB + kc * 32 + lhi * 8];
          s[n] = __builtin_amdgcn_mfma_f32_16x16x32_bf16(qf[kc], kf, s[n], 0, 0, 0);
        }
      }
      __builtin_amdgcn_s_setprio(0);

#pragma unroll
      for (int n = 0; n < 4; ++n)
#pragma unroll
        for (int r = 0; r < 4; ++r) {
          float v = s[n][r] * scale;
          if (last) {
            int qq = w * 16 + lhi * 4 + r;
            int kk = n * 16 + l15;
            if (kk > qq) v = -1e30f;
          }
          s[n][r] = v;
        }
      float mn[4], corr[4];
#pragma unroll
      for (int r = 0; r < 4; ++r) {
        float v = fmaxf(fmaxf(s[0][r], s[1][r]), fmaxf(s[2][r], s[3][r]));
#pragma unroll
        for (int off = 1; off < 16; off <<= 1) v = fmaxf(v, __shfl_xor(v, off, 64));
        mn[r] = fmaxf(m_r[r], v);
        corr[r] = __expf(m_r[r] - mn[r]);
        m_r[r] = mn[r];
      }
      float rs[4] = {0.f, 0.f, 0.f, 0.f};
#pragma unroll
      for (int n = 0; n < 4; ++n)
#pragma unroll
        for (int r = 0; r < 4; ++r) {
          float p = __expf(s[n][r] - mn[r]);
          rs[r] += p;
          Ps[w][(lhi * 4 + r) * PLDB + n * 16 + l15] = (bf16_t)p;
        }
#pragma unroll
      for (int r = 0; r < 4; ++r) {
        float v = rs[r];
#pragma unroll
        for (int off = 1; off < 16; off <<= 1) v += __shfl_xor(v, off, 64);
        l_r[r] = l_r[r] * corr[r] + v;
      }
#pragma unroll
      for (int n = 0; n < 8; ++n)
#pragma unroll
        for (int r = 0; r < 4; ++r) accO[n][r] *= corr[r];

      __builtin_amdgcn_s_setprio(1);
#pragma unroll
      for (int kc = 0; kc < 2; ++kc) {
        bf16x4 p0 = *(const bf16x4*)&Ps[w][l15 * PLDB + kc * 32 + lhi * 8];
        bf16x4 p1 = *(const bf16x4*)&Ps[w][l15 * PLDB + kc * 32 + lhi * 8 + 4];
        bf16x8 pf = __builtin_shufflevector(p0, p1, 0, 1, 2, 3, 4, 5, 6, 7);
#pragma unroll
        for (int n = 0; n < 8; ++n) {
          bf16x8 vf = *(const bf16x8*)&Vs[(n * 16 + l15) * VLDB + kc * 32 + lhi * 8];
          accO[n] = __builtin_amdgcn_mfma_f32_16x16x32_bf16(pf, vf, accO[n], 0, 0, 0);
        }
      }
      __builtin_amdgcn_s_setprio(0);

      __syncthreads();
      if (haveNext) WRITE_TILE();
      __syncthreads();
    }

    {
      float inv[4];
#pragma unroll
      for (int r = 0; r < 4; ++r) inv[r] = 1.0f / l_r[r];
#pragma unroll
      for (int n = 0; n < 8; ++n)
#pragma unroll
        for (int r = 0; r < 4; ++r) {
          size_t row = (size_t)(b * T_ + qt * 64 + w * 16 + lhi * 4 + r);
          Ob[row * (H_ * DH_) + h * DH_ + n * 16 + l15] = (bf16_t)(accO[n][r] * inv[r]);
        }
    }
  }
#undef LOAD_TILE
#undef WRITE_TILE
}

// ---------------- host ----------------
extern "C" void kernel_launch(void* const* d_in, const int* in_sizes, int n_in,
                              void* d_out, int out_size, void* d_ws, size_t ws_size,
                              hipStream_t stream) {
  (void)in_sizes; (void)n_in; (void)out_size; (void)ws_size;
  const float* x    = (const float*)d_in[0];
  const float* fr   = (const float*)d_in[1];
  // d_in[2] = mask (unused; causal handled analytically)
  const float* Wdq  = (const float*)d_in[3];
  const float* Wuq  = (const float*)d_in[4];
  const float* Wdkv = (const float*)d_in[5];
  const float* Wuk  = (const float*)d_in[6];
  const float* Wuv  = (const float*)d_in[7];
  const float* Wqr  = (const float*)d_in[8];
  const float* Wkr  = (const float*)d_in[9];
  const float* Wo   = (const float*)d_in[10];
  float* out = (float*)d_out;

  char* ws = (char*)d_ws;
  size_t off = 0;
  auto alloc = [&](size_t bytes) -> void* {
    void* p = ws + off;
    off += (bytes + 255) & ~(size_t)255;
    return p;
  };
  bf16_t* x_bf   = (bf16_t*)alloc((size_t)BT_ * DIM_ * 2);
  bf16_t* Bt1    = (bf16_t*)alloc((size_t)1152 * 2048 * 2);  // [Wdq(512) | Wdkv(512) | Wkr(128 pad)]
  bf16_t* Bt2    = (bf16_t*)alloc((size_t)3072 * 512 * 2);   // [Wuq(2048) | Wqr(1024)]
  bf16_t* Bt3    = (bf16_t*)alloc((size_t)4096 * 512 * 2);   // [Wuk(2048) | Wuv(2048)]
  bf16_t* Wo_t   = (bf16_t*)alloc((size_t)2048 * 2048 * 2);
  bf16_t* q_c    = (bf16_t*)alloc((size_t)BT_ * 512 * 2);
  bf16_t* kv_c   = (bf16_t*)alloc((size_t)BT_ * 512 * 2);
  bf16_t* Qbuf   = (bf16_t*)alloc((size_t)BT_ * QSTRIDE_ * 2);
  bf16_t* Kbuf   = (bf16_t*)alloc((size_t)BT_ * QSTRIDE_ * 2);
  bf16_t* Vt_g   = (bf16_t*)alloc((size_t)BT_ * 2048 * 2);
  bf16_t* AObuf  = (bf16_t*)alloc((size_t)BT_ * 2048 * 2);

  // 1) prep: weight transposes + x cast (9984 + 8192 blocks)
  prep<<<18176, dim3(32, 8), 0, stream>>>(x, Wdq, Wdkv, Wkr, Wuq, Wqr, Wuk, Wuv, Wo,
                                          x_bf, Bt1, Bt2, Bt3, Wo_t);

  // 2) gemm3: x @ [Wdq|Wdkv|Wkr] -> q_c, kv_c, rope-k broadcast into Kbuf
  gemm_bt<3><<<dim3(9, 32), 256, 0, stream>>>(x_bf, Bt1, q_c, kv_c, Kbuf, fr, BT_, 1088, 2048, 0);

  // 3) fused gemm4+gemm5: Qbuf (+rope-q), Kbuf heads, Vt (transposed in-epilogue)
  gemm45<<<dim3(56, 32), 256, 0, stream>>>(q_c, kv_c, Bt2, Bt3, Qbuf, Kbuf, Vt_g, fr);

  // 4) flash attention
  flash_attn3<<<512, 256, 0, stream>>>(Qbuf, Kbuf, Vt_g, AObuf);

  // 5) output projection -> fp32
  gemm_bt<1><<<dim3(16, 32), 256, 0, stream>>>(AObuf, Wo_t, out, nullptr, nullptr, nullptr, BT_, 2048, 2048, 2048);
}